// Round 13
// baseline (255.398 us; speedup 1.0000x reference)
//
#include <hip/hip_runtime.h>

#define TDIM 8192
#define NB 8
#define CD 512
#define SCALE 0.125f

typedef unsigned int u32;
typedef unsigned short u16;
typedef __bf16 bf16;
typedef bf16 bf16x8 __attribute__((ext_vector_type(8)));
typedef float f32x4 __attribute__((ext_vector_type(4)));
typedef u16 u16x4 __attribute__((ext_vector_type(4)));
typedef u16 u16x8 __attribute__((ext_vector_type(8)));

__device__ __forceinline__ u16 f2bf(float f) {
  u32 u = __float_as_uint(f);
  return (u16)((u + 0x7FFFu + ((u >> 16) & 1u)) >> 16);
}

__device__ __forceinline__ void gload16(const void* g, void* l) {
  __builtin_amdgcn_global_load_lds((const __attribute__((address_space(1))) u32*)g,
                                   (__attribute__((address_space(3))) u32*)l, 16, 0, 0);
}

// ---------------- K0: transpose + cast q: [b][c][t] f32 -> qT [b][t][c] bf16 ----------------
__global__ __launch_bounds__(256) void k_tq(const float* __restrict__ q, u16* __restrict__ qT) {
  __shared__ float tile[64][65];
  const int b = blockIdx.z, cb = blockIdx.y * 64, tb = blockIdx.x * 64;
  const int tid = threadIdx.x, r = tid >> 2, qd = tid & 3;
  const float* src = q + ((size_t)(b * CD + cb + r)) * TDIM + tb;
#pragma unroll
  for (int j = 0; j < 4; ++j) {
    const float4 v = *(const float4*)(src + j * 16 + qd * 4);
    tile[r][j * 16 + qd * 4 + 0] = v.x;
    tile[r][j * 16 + qd * 4 + 1] = v.y;
    tile[r][j * 16 + qd * 4 + 2] = v.z;
    tile[r][j * 16 + qd * 4 + 3] = v.w;
  }
  __syncthreads();
  u16x8 o0, o1;
#pragma unroll
  for (int i = 0; i < 8; ++i) o0[i] = f2bf(tile[qd * 16 + i][r]);
#pragma unroll
  for (int i = 0; i < 8; ++i) o1[i] = f2bf(tile[qd * 16 + 8 + i][r]);
  u16* dst = qT + ((size_t)b * TDIM + tb + r) * CD + cb + qd * 16;
  *(u16x8*)dst = o0;
  *(u16x8*)(dst + 8) = o1;
}

// ---------------- cast weights: Wq (512x512) ++ Wkv (1024x512) -> Wall bf16 ----------------
__global__ __launch_bounds__(256) void k_cast_w(const float* __restrict__ Wq, const float* __restrict__ Wkv,
                                                u16* __restrict__ Wall) {
  const int idx = (blockIdx.x * 256 + threadIdx.x) * 4;
  float4 v;
  if (idx < 512 * 512) v = *(const float4*)(Wq + idx);
  else                 v = *(const float4*)(Wkv + (idx - 512 * 512));
  u16x4 p;
  p[0] = f2bf(v.x); p[1] = f2bf(v.y); p[2] = f2bf(v.z); p[3] = f2bf(v.w);
  *(u16x4*)(Wall + idx) = p;
}

// ============ 128x128 GEMM core, BK=32, 4 waves (2M x 2N, wave=64x64), ring-3 LDS 3x16KB ============
// OCCUPANCY PUSH vs R12: kt body subtiled into 2x2 MFMA blocks so only 4 fragments (16 regs) are
// live (was 8 frags/32 regs): reads 8->12 b128/kt (LDS port ~45%, unsaturated), total regs
// acc(64 AGPR)+frags(16)+addr(~30) ~= 110 <= 128 -> __launch_bounds__(256,4) admits 4 waves/EU
// (16 waves/CU). Spill tell = WRITE_SIZE anomaly (R7 signature). Swizzle (R12) + sched_barrier
// fences (R11, rule #18) unchanged.
__device__ __forceinline__ void stage128(const u16* __restrict__ Aw, const u16* __restrict__ Bw,
                                         char* buf, int w, int lane, int kt) {
  const int r4 = lane >> 2, c4 = lane & 3;
  const int cs = c4 ^ ((r4 >> 1) & 3);              // inverse-swizzled source chunk
  const size_t go = (size_t)r4 * CD + kt * 32 + cs * 8;
  gload16(Aw + go, buf + w * 2048);                     // A rows strip..+16
  gload16(Aw + 16 * CD + go, buf + w * 2048 + 1024);    // A rows strip+16..+32
  gload16(Bw + go, buf + 8192 + w * 2048);              // B rows strip..+16
  gload16(Bw + 16 * CD + go, buf + 8192 + w * 2048 + 1024);
}

__device__ __forceinline__ void gemm128(const u16* __restrict__ Aw, const u16* __restrict__ Bw,
                                        char* lds, f32x4 (&acc)[4][4]) {
  const int tid = threadIdx.x, lane = tid & 63, w = tid >> 6;
  const int wr = w >> 1, wc = w & 1;
  const int lo16 = lane & 15, hi4 = lane >> 4;
  stage128(Aw, Bw, lds, w, lane, 0);
  stage128(Aw, Bw, lds + 16384, w, lane, 1);
#pragma unroll
  for (int kt = 0; kt < 16; ++kt) {
    if (kt < 15) asm volatile("s_waitcnt vmcnt(4)" ::: "memory");   // stage(kt) landed; (kt+1) in flight
    else         asm volatile("s_waitcnt vmcnt(0)" ::: "memory");
    __builtin_amdgcn_sched_barrier(0);
    __builtin_amdgcn_s_barrier();
    __builtin_amdgcn_sched_barrier(0);
    char* bc = lds + (kt % 3) * 16384;
    if (kt < 14)
      stage128(Aw, Bw, lds + ((kt + 2) % 3) * 16384, w, lane, kt + 2);
    __builtin_amdgcn_sched_barrier(0);
#pragma unroll
    for (int bh2 = 0; bh2 < 2; ++bh2) {
      bf16x8 bv[2];
#pragma unroll
      for (int j = 0; j < 2; ++j) {
        const int rowB = wc * 64 + (bh2 * 2 + j) * 16 + lo16;
        bv[j] = *(const bf16x8*)(bc + 8192 + rowB * 64 + ((hi4 ^ ((rowB >> 1) & 3)) << 4));
      }
#pragma unroll
      for (int ah2 = 0; ah2 < 2; ++ah2) {
        bf16x8 av[2];
#pragma unroll
        for (int i = 0; i < 2; ++i) {
          const int rowA = wr * 64 + (ah2 * 2 + i) * 16 + lo16;
          av[i] = *(const bf16x8*)(bc + rowA * 64 + ((hi4 ^ ((rowA >> 1) & 3)) << 4));
        }
#pragma unroll
        for (int i = 0; i < 2; ++i)
#pragma unroll
          for (int j = 0; j < 2; ++j)
            acc[ah2 * 2 + i][bh2 * 2 + j] = __builtin_amdgcn_mfma_f32_16x16x32_bf16(
                av[i], bv[j], acc[ah2 * 2 + i][bh2 * 2 + j], 0, 0, 0);
      }
    }
  }
  __syncthreads();   // full fence: ring reads done before epilogue reuses LDS
}

// ---------------- K1: proj GEMM + fused softmax/exp/rowsum + fused ctx accumulation ----------------
// M-tiles per batch (128 rows each): mt 0..3 = qh rows mt*128; mt 4..11 = head m = mt-4, rows =
// (k: 512+m*64..+64) ++ (v: 1024+m*64..+64). kv-blocks compute ctx[m][d][e] += ek@v^T from the
// epilogue LDS tile (4 waves x 32x32 quadrant); ek/v never hit HBM.
// 6144 blocks = 8 XCD x 768; XCD x owns batch x; 12 consecutive wg share one qT B-tile.
__global__ __launch_bounds__(256, 4) void k_proj(const u16* __restrict__ Wall, const u16* __restrict__ qT,
                                                 u16* __restrict__ qhT, float* __restrict__ ctx,
                                                 float* __restrict__ rowsum) {
  __shared__ __align__(16) char LDS[49152];   // ring-3 48KB; epilogue reuses first 32KB
  const int lid = blockIdx.x;
  const int wg = (lid & 7) * 768 + (lid >> 3);
  const int b = wg / 768, r = wg % 768;
  const int mt = r % 12, nt = r / 12;
  const int t0 = nt * 128;
  const int tid = threadIdx.x, lane = tid & 63, w = tid >> 6;
  const int wr = w >> 1, wc = w & 1, lo16 = lane & 15, hi4 = lane >> 4;
  const bool isQH = mt < 4;
  const int m = mt - 4;
  const u16* Aw;   // this wave's 32-row staging strip
  if (isQH)       Aw = Wall + (size_t)(mt * 128 + w * 32) * CD;
  else if (w < 2) Aw = Wall + (size_t)(512 + m * 64 + w * 32) * CD;          // k rows
  else            Aw = Wall + (size_t)(1024 + m * 64 + (w - 2) * 32) * CD;   // v rows
  const u16* Bw = qT + ((size_t)b * TDIM + t0 + w * 32) * CD;
  f32x4 acc[4][4] = {};
  gemm128(Aw, Bw, LDS, acc);
  char* lds = LDS;
  if (isQH) {
    const int row0 = mt * 128;
    // ---- qh path: wave owns head (row0/64 + wr): 64 rows. softmax over rows per column, *SCALE.
#pragma unroll
    for (int am = 0; am < 4; ++am)
#pragma unroll
      for (int an = 0; an < 4; ++an)
#pragma unroll
        for (int r2 = 0; r2 < 4; ++r2) acc[am][an][r2] = __expf(acc[am][an][r2]);
#pragma unroll
    for (int an = 0; an < 4; ++an) {
      float s = 0.f;
#pragma unroll
      for (int am = 0; am < 4; ++am)
#pragma unroll
        for (int r2 = 0; r2 < 4; ++r2) s += acc[am][an][r2];
      s += __shfl_xor(s, 16);
      s += __shfl_xor(s, 32);
      const float inv = SCALE / s;
#pragma unroll
      for (int am = 0; am < 4; ++am)
#pragma unroll
        for (int r2 = 0; r2 < 4; ++r2) acc[am][an][r2] *= inv;
    }
    // transposed LDS tile [t 128][c 128] bf16 (32 KB), 16B-gran XOR swizzle
#pragma unroll
    for (int am = 0; am < 4; ++am)
#pragma unroll
      for (int an = 0; an < 4; ++an) {
        const int tl = wc * 64 + an * 16 + lo16;
        const int cb2 = (wr * 64 + am * 16 + hi4 * 4) * 2;
        u16x4 p;
#pragma unroll
        for (int r2 = 0; r2 < 4; ++r2) p[r2] = f2bf(acc[am][an][r2]);
        *(u16x4*)(lds + tl * 256 + ((cb2 & ~15) ^ ((tl & 7) << 4)) + (cb2 & 8)) = p;
      }
    __syncthreads();
#pragma unroll
    for (int pp = 0; pp < 8; ++pp) {
      const int tr = pp * 16 + (tid >> 4), chk = tid & 15;
      const uint4 val = *(const uint4*)(lds + tr * 256 + ((chk * 16) ^ ((tr & 7) << 4)));
      *(uint4*)(qhT + ((size_t)b * TDIM + t0 + tr) * CD + row0 + chk * 8) = val;
    }
  } else {
    // ---- kv path: tile rows 0..63 = ek rows (c = m*64 + row), 64..127 = v rows (same c).
    if (wr == 0) {   // k-half waves: exp + rowsum
#pragma unroll
      for (int am = 0; am < 4; ++am)
#pragma unroll
        for (int an = 0; an < 4; ++an)
#pragma unroll
          for (int r2 = 0; r2 < 4; ++r2) acc[am][an][r2] = __expf(acc[am][an][r2]);
#pragma unroll
      for (int am = 0; am < 4; ++am)
#pragma unroll
        for (int r2 = 0; r2 < 4; ++r2) {
          float s = acc[am][0][r2] + acc[am][1][r2] + acc[am][2][r2] + acc[am][3][r2];
          s += __shfl_xor(s, 1); s += __shfl_xor(s, 2);
          s += __shfl_xor(s, 4); s += __shfl_xor(s, 8);
          if (lo16 == 0)
            unsafeAtomicAdd(rowsum + b * CD + m * 64 + am * 16 + hi4 * 4 + r2, s);
        }
    }
    // natural LDS tile [row 128][t 128] bf16 (32 KB), 16B-gran XOR swizzle; 2B scattered writes
#pragma unroll
    for (int am = 0; am < 4; ++am)
#pragma unroll
      for (int an = 0; an < 4; ++an) {
        const int tl2 = (wc * 64 + an * 16 + lo16) * 2;
#pragma unroll
        for (int r2 = 0; r2 < 4; ++r2) {
          const int cl = wr * 64 + am * 16 + hi4 * 4 + r2;
          *(u16*)(lds + cl * 256 + ((tl2 & ~15) ^ ((cl & 7) << 4)) + (tl2 & 15)) = f2bf(acc[am][an][r2]);
        }
      }
    __syncthreads();
    // ctx GEMM from LDS: wave w -> quadrant d0=(w&1)*32, e0=(w>>1)*32 of head m's 64x64 ctx.
    const int d0 = (w & 1) * 32, e0 = (w >> 1) * 32;
    f32x4 cacc[2][2] = {};
#pragma unroll
    for (int tk = 0; tk < 4; ++tk) {
      bf16x8 ea[2], vv[2];
#pragma unroll
      for (int dm = 0; dm < 2; ++dm) {
        const int rowE = d0 + dm * 16 + lo16;
        ea[dm] = *(const bf16x8*)(lds + rowE * 256 + ((tk * 64 + hi4 * 16) ^ ((rowE & 7) << 4)));
      }
#pragma unroll
      for (int de = 0; de < 2; ++de) {
        const int rowV = 64 + e0 + de * 16 + lo16;
        vv[de] = *(const bf16x8*)(lds + rowV * 256 + ((tk * 64 + hi4 * 16) ^ ((rowV & 7) << 4)));
      }
#pragma unroll
      for (int dm = 0; dm < 2; ++dm)
#pragma unroll
        for (int de = 0; de < 2; ++de)
          cacc[dm][de] = __builtin_amdgcn_mfma_f32_16x16x32_bf16(ea[dm], vv[de], cacc[dm][de], 0, 0, 0);
    }
    float* cdst = ctx + ((size_t)(b * 8 + m)) * 4096;
#pragma unroll
    for (int dm = 0; dm < 2; ++dm)
#pragma unroll
      for (int de = 0; de < 2; ++de)
#pragma unroll
        for (int r2 = 0; r2 < 4; ++r2)
          unsafeAtomicAdd(cdst + (d0 + dm * 16 + hi4 * 4 + r2) * 64 + e0 + de * 16 + lo16,
                          cacc[dm][de][r2]);
  }
}

// ---------------- K2b: Weff[b][o][64h+d] = sum_e Wout[o][64h+e] * ctx[d][e] / rowsum[d] ----------------
__global__ __launch_bounds__(256) void k_weff(const float* __restrict__ Wout, const float* __restrict__ ctx,
                                              const float* __restrict__ rowsum, u16* __restrict__ Weff) {
  __shared__ float cn[64][65];
  __shared__ float rsin[64];
  const int bh = blockIdx.y, b = bh >> 3, h = bh & 7;
  const int o0 = blockIdx.x * 64;
  const int tid = threadIdx.x;
  if (tid < 64) rsin[tid] = 1.f / rowsum[b * CD + h * 64 + tid];
  __syncthreads();
  const float* csrc = ctx + (size_t)bh * 4096;
#pragma unroll
  for (int i = 0; i < 16; ++i) {
    const int idx = tid + 256 * i;
    cn[idx >> 6][idx & 63] = csrc[idx] * rsin[idx >> 6];
  }
  __syncthreads();
  const int o = o0 + (tid >> 2), dq = (tid & 3) * 16;
  const float* wrow = Wout + (size_t)o * CD + h * 64;
  float a[16] = {};
  for (int e2 = 0; e2 < 64; ++e2) {
    const float wv = wrow[e2];
#pragma unroll
    for (int i = 0; i < 16; ++i) a[i] += wv * cn[dq + i][e2];
  }
  u16x8 p0, p1;
#pragma unroll
  for (int i = 0; i < 8; ++i) { p0[i] = f2bf(a[i]); p1[i] = f2bf(a[8 + i]); }
  u16* dst = Weff + ((size_t)(b * CD + o)) * CD + h * 64 + dq;
  *(u16x8*)dst = p0;
  *(u16x8*)(dst + 8) = p1;
}

// ---------------- K3: final[b][o][t] = Weff[b] @ qhT + b_out ----------------
// 2048 blocks = 8 XCD x 256.
__global__ __launch_bounds__(256, 4) void k_final(const u16* __restrict__ Weff, const u16* __restrict__ qhT,
                                                  const float* __restrict__ bias, float* __restrict__ out) {
  __shared__ __align__(16) char LDS[49152];
  const int lid = blockIdx.x;
  const int wg = (lid & 7) * 256 + (lid >> 3);
  const int b = wg >> 8, r = wg & 255;
  const int mt = r & 3, nt = r >> 2;
  const int row0 = mt * 128, t0 = nt * 128;
  const int tid = threadIdx.x, lane = tid & 63, w = tid >> 6;
  const int wr = w >> 1, wc = w & 1, lo16 = lane & 15, hi4 = lane >> 4;
  const u16* Aw = Weff + ((size_t)(b * CD + row0 + w * 32)) * CD;
  const u16* Bw = qhT + ((size_t)b * TDIM + t0 + w * 32) * CD;
  f32x4 acc[4][4] = {};
  gemm128(Aw, Bw, LDS, acc);
#pragma unroll
  for (int am = 0; am < 4; ++am)
#pragma unroll
    for (int r2 = 0; r2 < 4; ++r2) {
      const int o = row0 + wr * 64 + am * 16 + hi4 * 4 + r2;
      const float bo = bias[o];
      float* orow = out + ((size_t)(b * CD + o)) * TDIM + t0 + wc * 64 + lo16;
#pragma unroll
      for (int an = 0; an < 4; ++an)
        orow[an * 16] = acc[am][an][r2] + bo;
    }
}

extern "C" void kernel_launch(void* const* d_in, const int* in_sizes, int n_in,
                              void* d_out, int out_size, void* d_ws, size_t ws_size,
                              hipStream_t stream) {
  const float* q    = (const float*)d_in[0];
  const float* Wq   = (const float*)d_in[1];
  const float* Wkv  = (const float*)d_in[2];
  const float* Wout = (const float*)d_in[3];
  const float* bout = (const float*)d_in[4];
  float* out = (float*)d_out;
  char* ws = (char*)d_ws;
  const size_t SZ = (size_t)NB * CD * TDIM * 2;   // 64 MiB per bf16 [8][512][8192] buffer
  u16* qT  = (u16*)ws;
  u16* qhT = (u16*)(ws + SZ);
  char* base = ws + 2 * SZ;
  u16* Wall   = (u16*)base;                       // 1.5 MB
  float* ctx  = (float*)(base + (2u << 20));      // 1 MB
  float* rsum = (float*)(base + (3u << 20));      // 16 KB
  u16* Weff   = (u16*)(base + (4u << 20));        // 4 MB
  (void)in_sizes; (void)n_in; (void)out_size; (void)ws_size;

  hipMemsetAsync(base + (2u << 20), 0, 2u << 20, stream);  // zero ctx + rowsum accumulators
  k_tq    <<<dim3(128, 8, 8), 256, 0, stream>>>(q, qT);
  k_cast_w<<<dim3(768), 256, 0, stream>>>(Wq, Wkv, Wall);
  k_proj  <<<dim3(6144), 256, 0, stream>>>(Wall, qT, qhT, ctx, rsum);
  k_weff  <<<dim3(8, 64), 256, 0, stream>>>(Wout, ctx, rsum, Weff);
  k_final <<<dim3(2048), 256, 0, stream>>>(Weff, qhT, bout, out);
}

// Round 14
// 243.529 us; speedup vs baseline: 1.0487x; 1.0487x over previous
//
#include <hip/hip_runtime.h>

#define TDIM 8192
#define NB 8
#define CD 512
#define SCALE 0.125f

typedef unsigned int u32;
typedef unsigned short u16;
typedef __bf16 bf16;
typedef bf16 bf16x8 __attribute__((ext_vector_type(8)));
typedef float f32x4 __attribute__((ext_vector_type(4)));
typedef u16 u16x4 __attribute__((ext_vector_type(4)));
typedef u16 u16x8 __attribute__((ext_vector_type(8)));

__device__ __forceinline__ u16 f2bf(float f) {
  u32 u = __float_as_uint(f);
  return (u16)((u + 0x7FFFu + ((u >> 16) & 1u)) >> 16);
}

__device__ __forceinline__ void gload16(const void* g, void* l) {
  __builtin_amdgcn_global_load_lds((const __attribute__((address_space(1))) u32*)g,
                                   (__attribute__((address_space(3))) u32*)l, 16, 0, 0);
}

// ---------------- K0: transpose + cast q: [b][c][t] f32 -> qT [b][t][c] bf16 ----------------
__global__ __launch_bounds__(256) void k_tq(const float* __restrict__ q, u16* __restrict__ qT) {
  __shared__ float tile[64][65];
  const int b = blockIdx.z, cb = blockIdx.y * 64, tb = blockIdx.x * 64;
  const int tid = threadIdx.x, r = tid >> 2, qd = tid & 3;
  const float* src = q + ((size_t)(b * CD + cb + r)) * TDIM + tb;
#pragma unroll
  for (int j = 0; j < 4; ++j) {
    const float4 v = *(const float4*)(src + j * 16 + qd * 4);
    tile[r][j * 16 + qd * 4 + 0] = v.x;
    tile[r][j * 16 + qd * 4 + 1] = v.y;
    tile[r][j * 16 + qd * 4 + 2] = v.z;
    tile[r][j * 16 + qd * 4 + 3] = v.w;
  }
  __syncthreads();
  u16x8 o0, o1;
#pragma unroll
  for (int i = 0; i < 8; ++i) o0[i] = f2bf(tile[qd * 16 + i][r]);
#pragma unroll
  for (int i = 0; i < 8; ++i) o1[i] = f2bf(tile[qd * 16 + 8 + i][r]);
  u16* dst = qT + ((size_t)b * TDIM + tb + r) * CD + cb + qd * 16;
  *(u16x8*)dst = o0;
  *(u16x8*)(dst + 8) = o1;
}

// ---------------- cast weights: Wq (512x512) ++ Wkv (1024x512) -> Wall bf16 ----------------
__global__ __launch_bounds__(256) void k_cast_w(const float* __restrict__ Wq, const float* __restrict__ Wkv,
                                                u16* __restrict__ Wall) {
  const int idx = (blockIdx.x * 256 + threadIdx.x) * 4;
  float4 v;
  if (idx < 512 * 512) v = *(const float4*)(Wq + idx);
  else                 v = *(const float4*)(Wkv + (idx - 512 * 512));
  u16x4 p;
  p[0] = f2bf(v.x); p[1] = f2bf(v.y); p[2] = f2bf(v.z); p[3] = f2bf(v.w);
  *(u16x4*)(Wall + idx) = p;
}

// ============ 128x128 GEMM core, BK=32, 4 waves (2M x 2N, wave=64x64), ring-3 LDS 3x16KB ============
// R12 structure (best verified) + T5 setprio around the MFMA cluster: ~2.4 co-resident blocks/CU
// drift to different kt phases; priority lets MFMA-phase waves win SIMD issue vs other blocks'
// staging waves. Swizzle (R12) + sched_barrier fences (R11, rule #18) unchanged.
__device__ __forceinline__ void stage128(const u16* __restrict__ Aw, const u16* __restrict__ Bw,
                                         char* buf, int w, int lane, int kt) {
  const int r4 = lane >> 2, c4 = lane & 3;
  const int cs = c4 ^ ((r4 >> 1) & 3);              // inverse-swizzled source chunk
  const size_t go = (size_t)r4 * CD + kt * 32 + cs * 8;
  gload16(Aw + go, buf + w * 2048);                     // A rows strip..+16
  gload16(Aw + 16 * CD + go, buf + w * 2048 + 1024);    // A rows strip+16..+32
  gload16(Bw + go, buf + 8192 + w * 2048);              // B rows strip..+16
  gload16(Bw + 16 * CD + go, buf + 8192 + w * 2048 + 1024);
}

__device__ __forceinline__ void gemm128(const u16* __restrict__ Aw, const u16* __restrict__ Bw,
                                        char* lds, f32x4 (&acc)[4][4]) {
  const int tid = threadIdx.x, lane = tid & 63, w = tid >> 6;
  const int wr = w >> 1, wc = w & 1;
  const int lo16 = lane & 15, hi4 = lane >> 4;
  stage128(Aw, Bw, lds, w, lane, 0);
  stage128(Aw, Bw, lds + 16384, w, lane, 1);
#pragma unroll
  for (int kt = 0; kt < 16; ++kt) {
    if (kt < 15) asm volatile("s_waitcnt vmcnt(4)" ::: "memory");   // stage(kt) landed; (kt+1) in flight
    else         asm volatile("s_waitcnt vmcnt(0)" ::: "memory");
    __builtin_amdgcn_sched_barrier(0);
    __builtin_amdgcn_s_barrier();
    __builtin_amdgcn_sched_barrier(0);
    char* bc = lds + (kt % 3) * 16384;
    if (kt < 14)
      stage128(Aw, Bw, lds + ((kt + 2) % 3) * 16384, w, lane, kt + 2);
    __builtin_amdgcn_sched_barrier(0);
    bf16x8 av[4], bv[4];
#pragma unroll
    for (int am = 0; am < 4; ++am) {
      const int rowA = wr * 64 + am * 16 + lo16;
      av[am] = *(const bf16x8*)(bc + rowA * 64 + ((hi4 ^ ((rowA >> 1) & 3)) << 4));
    }
#pragma unroll
    for (int an = 0; an < 4; ++an) {
      const int rowB = wc * 64 + an * 16 + lo16;
      bv[an] = *(const bf16x8*)(bc + 8192 + rowB * 64 + ((hi4 ^ ((rowB >> 1) & 3)) << 4));
    }
    __builtin_amdgcn_s_setprio(1);
#pragma unroll
    for (int am = 0; am < 4; ++am)
#pragma unroll
      for (int an = 0; an < 4; ++an)
        acc[am][an] = __builtin_amdgcn_mfma_f32_16x16x32_bf16(av[am], bv[an], acc[am][an], 0, 0, 0);
    __builtin_amdgcn_s_setprio(0);
  }
  __syncthreads();   // full fence: ring reads done before epilogue reuses LDS
}

// ---------------- K1: proj GEMM + fused softmax/exp/rowsum + fused ctx accumulation ----------------
// M-tiles per batch (128 rows each): mt 0..3 = qh rows mt*128; mt 4..11 = head m = mt-4, rows =
// (k: 512+m*64..+64) ++ (v: 1024+m*64..+64). kv-blocks compute ctx[m][d][e] += ek@v^T from the
// epilogue LDS tile (4 waves x 32x32 quadrant); ek/v never hit HBM.
// 6144 blocks = 8 XCD x 768; XCD x owns batch x; 12 consecutive wg share one qT B-tile.
__global__ __launch_bounds__(256, 3) void k_proj(const u16* __restrict__ Wall, const u16* __restrict__ qT,
                                                 u16* __restrict__ qhT, float* __restrict__ ctx,
                                                 float* __restrict__ rowsum) {
  __shared__ __align__(16) char LDS[49152];   // ring-3 48KB; epilogue reuses first 32KB
  const int lid = blockIdx.x;
  const int wg = (lid & 7) * 768 + (lid >> 3);
  const int b = wg / 768, r = wg % 768;
  const int mt = r % 12, nt = r / 12;
  const int t0 = nt * 128;
  const int tid = threadIdx.x, lane = tid & 63, w = tid >> 6;
  const int wr = w >> 1, wc = w & 1, lo16 = lane & 15, hi4 = lane >> 4;
  const bool isQH = mt < 4;
  const int m = mt - 4;
  const u16* Aw;   // this wave's 32-row staging strip
  if (isQH)       Aw = Wall + (size_t)(mt * 128 + w * 32) * CD;
  else if (w < 2) Aw = Wall + (size_t)(512 + m * 64 + w * 32) * CD;          // k rows
  else            Aw = Wall + (size_t)(1024 + m * 64 + (w - 2) * 32) * CD;   // v rows
  const u16* Bw = qT + ((size_t)b * TDIM + t0 + w * 32) * CD;
  f32x4 acc[4][4] = {};
  gemm128(Aw, Bw, LDS, acc);
  char* lds = LDS;
  if (isQH) {
    const int row0 = mt * 128;
    // ---- qh path: wave owns head (row0/64 + wr): 64 rows. softmax over rows per column, *SCALE.
#pragma unroll
    for (int am = 0; am < 4; ++am)
#pragma unroll
      for (int an = 0; an < 4; ++an)
#pragma unroll
        for (int r2 = 0; r2 < 4; ++r2) acc[am][an][r2] = __expf(acc[am][an][r2]);
#pragma unroll
    for (int an = 0; an < 4; ++an) {
      float s = 0.f;
#pragma unroll
      for (int am = 0; am < 4; ++am)
#pragma unroll
        for (int r2 = 0; r2 < 4; ++r2) s += acc[am][an][r2];
      s += __shfl_xor(s, 16);
      s += __shfl_xor(s, 32);
      const float inv = SCALE / s;
#pragma unroll
      for (int am = 0; am < 4; ++am)
#pragma unroll
        for (int r2 = 0; r2 < 4; ++r2) acc[am][an][r2] *= inv;
    }
    // transposed LDS tile [t 128][c 128] bf16 (32 KB), 16B-gran XOR swizzle
#pragma unroll
    for (int am = 0; am < 4; ++am)
#pragma unroll
      for (int an = 0; an < 4; ++an) {
        const int tl = wc * 64 + an * 16 + lo16;
        const int cb2 = (wr * 64 + am * 16 + hi4 * 4) * 2;
        u16x4 p;
#pragma unroll
        for (int r2 = 0; r2 < 4; ++r2) p[r2] = f2bf(acc[am][an][r2]);
        *(u16x4*)(lds + tl * 256 + ((cb2 & ~15) ^ ((tl & 7) << 4)) + (cb2 & 8)) = p;
      }
    __syncthreads();
#pragma unroll
    for (int pp = 0; pp < 8; ++pp) {
      const int tr = pp * 16 + (tid >> 4), chk = tid & 15;
      const uint4 val = *(const uint4*)(lds + tr * 256 + ((chk * 16) ^ ((tr & 7) << 4)));
      *(uint4*)(qhT + ((size_t)b * TDIM + t0 + tr) * CD + row0 + chk * 8) = val;
    }
  } else {
    // ---- kv path: tile rows 0..63 = ek rows (c = m*64 + row), 64..127 = v rows (same c).
    if (wr == 0) {   // k-half waves: exp + rowsum
#pragma unroll
      for (int am = 0; am < 4; ++am)
#pragma unroll
        for (int an = 0; an < 4; ++an)
#pragma unroll
          for (int r2 = 0; r2 < 4; ++r2) acc[am][an][r2] = __expf(acc[am][an][r2]);
#pragma unroll
      for (int am = 0; am < 4; ++am)
#pragma unroll
        for (int r2 = 0; r2 < 4; ++r2) {
          float s = acc[am][0][r2] + acc[am][1][r2] + acc[am][2][r2] + acc[am][3][r2];
          s += __shfl_xor(s, 1); s += __shfl_xor(s, 2);
          s += __shfl_xor(s, 4); s += __shfl_xor(s, 8);
          if (lo16 == 0)
            unsafeAtomicAdd(rowsum + b * CD + m * 64 + am * 16 + hi4 * 4 + r2, s);
        }
    }
    // natural LDS tile [row 128][t 128] bf16 (32 KB), 16B-gran XOR swizzle; 2B scattered writes
#pragma unroll
    for (int am = 0; am < 4; ++am)
#pragma unroll
      for (int an = 0; an < 4; ++an) {
        const int tl2 = (wc * 64 + an * 16 + lo16) * 2;
#pragma unroll
        for (int r2 = 0; r2 < 4; ++r2) {
          const int cl = wr * 64 + am * 16 + hi4 * 4 + r2;
          *(u16*)(lds + cl * 256 + ((tl2 & ~15) ^ ((cl & 7) << 4)) + (tl2 & 15)) = f2bf(acc[am][an][r2]);
        }
      }
    __syncthreads();
    // ctx GEMM from LDS: wave w -> quadrant d0=(w&1)*32, e0=(w>>1)*32 of head m's 64x64 ctx.
    const int d0 = (w & 1) * 32, e0 = (w >> 1) * 32;
    f32x4 cacc[2][2] = {};
#pragma unroll
    for (int tk = 0; tk < 4; ++tk) {
      bf16x8 ea[2], vv[2];
#pragma unroll
      for (int dm = 0; dm < 2; ++dm) {
        const int rowE = d0 + dm * 16 + lo16;
        ea[dm] = *(const bf16x8*)(lds + rowE * 256 + ((tk * 64 + hi4 * 16) ^ ((rowE & 7) << 4)));
      }
#pragma unroll
      for (int de = 0; de < 2; ++de) {
        const int rowV = 64 + e0 + de * 16 + lo16;
        vv[de] = *(const bf16x8*)(lds + rowV * 256 + ((tk * 64 + hi4 * 16) ^ ((rowV & 7) << 4)));
      }
#pragma unroll
      for (int dm = 0; dm < 2; ++dm)
#pragma unroll
        for (int de = 0; de < 2; ++de)
          cacc[dm][de] = __builtin_amdgcn_mfma_f32_16x16x32_bf16(ea[dm], vv[de], cacc[dm][de], 0, 0, 0);
    }
    float* cdst = ctx + ((size_t)(b * 8 + m)) * 4096;
#pragma unroll
    for (int dm = 0; dm < 2; ++dm)
#pragma unroll
      for (int de = 0; de < 2; ++de)
#pragma unroll
        for (int r2 = 0; r2 < 4; ++r2)
          unsafeAtomicAdd(cdst + (d0 + dm * 16 + hi4 * 4 + r2) * 64 + e0 + de * 16 + lo16,
                          cacc[dm][de][r2]);
  }
}

// ---------------- K2b: Weff[b][o][64h+d] = sum_e Wout[o][64h+e] * ctx[d][e] / rowsum[d] ----------------
__global__ __launch_bounds__(256) void k_weff(const float* __restrict__ Wout, const float* __restrict__ ctx,
                                              const float* __restrict__ rowsum, u16* __restrict__ Weff) {
  __shared__ float cn[64][65];
  __shared__ float rsin[64];
  const int bh = blockIdx.y, b = bh >> 3, h = bh & 7;
  const int o0 = blockIdx.x * 64;
  const int tid = threadIdx.x;
  if (tid < 64) rsin[tid] = 1.f / rowsum[b * CD + h * 64 + tid];
  __syncthreads();
  const float* csrc = ctx + (size_t)bh * 4096;
#pragma unroll
  for (int i = 0; i < 16; ++i) {
    const int idx = tid + 256 * i;
    cn[idx >> 6][idx & 63] = csrc[idx] * rsin[idx >> 6];
  }
  __syncthreads();
  const int o = o0 + (tid >> 2), dq = (tid & 3) * 16;
  const float* wrow = Wout + (size_t)o * CD + h * 64;
  float a[16] = {};
  for (int e2 = 0; e2 < 64; ++e2) {
    const float wv = wrow[e2];
#pragma unroll
    for (int i = 0; i < 16; ++i) a[i] += wv * cn[dq + i][e2];
  }
  u16x8 p0, p1;
#pragma unroll
  for (int i = 0; i < 8; ++i) { p0[i] = f2bf(a[i]); p1[i] = f2bf(a[8 + i]); }
  u16* dst = Weff + ((size_t)(b * CD + o)) * CD + h * 64 + dq;
  *(u16x8*)dst = p0;
  *(u16x8*)(dst + 8) = p1;
}

// ---------------- K3: final[b][o][t] = Weff[b] @ qhT + b_out ----------------
// 2048 blocks = 8 XCD x 256.
__global__ __launch_bounds__(256, 3) void k_final(const u16* __restrict__ Weff, const u16* __restrict__ qhT,
                                                  const float* __restrict__ bias, float* __restrict__ out) {
  __shared__ __align__(16) char LDS[49152];
  const int lid = blockIdx.x;
  const int wg = (lid & 7) * 256 + (lid >> 3);
  const int b = wg >> 8, r = wg & 255;
  const int mt = r & 3, nt = r >> 2;
  const int row0 = mt * 128, t0 = nt * 128;
  const int tid = threadIdx.x, lane = tid & 63, w = tid >> 6;
  const int wr = w >> 1, wc = w & 1, lo16 = lane & 15, hi4 = lane >> 4;
  const u16* Aw = Weff + ((size_t)(b * CD + row0 + w * 32)) * CD;
  const u16* Bw = qhT + ((size_t)b * TDIM + t0 + w * 32) * CD;
  f32x4 acc[4][4] = {};
  gemm128(Aw, Bw, LDS, acc);
#pragma unroll
  for (int am = 0; am < 4; ++am)
#pragma unroll
    for (int r2 = 0; r2 < 4; ++r2) {
      const int o = row0 + wr * 64 + am * 16 + hi4 * 4 + r2;
      const float bo = bias[o];
      float* orow = out + ((size_t)(b * CD + o)) * TDIM + t0 + wc * 64 + lo16;
#pragma unroll
      for (int an = 0; an < 4; ++an)
        orow[an * 16] = acc[am][an][r2] + bo;
    }
}

extern "C" void kernel_launch(void* const* d_in, const int* in_sizes, int n_in,
                              void* d_out, int out_size, void* d_ws, size_t ws_size,
                              hipStream_t stream) {
  const float* q    = (const float*)d_in[0];
  const float* Wq   = (const float*)d_in[1];
  const float* Wkv  = (const float*)d_in[2];
  const float* Wout = (const float*)d_in[3];
  const float* bout = (const float*)d_in[4];
  float* out = (float*)d_out;
  char* ws = (char*)d_ws;
  const size_t SZ = (size_t)NB * CD * TDIM * 2;   // 64 MiB per bf16 [8][512][8192] buffer
  u16* qT  = (u16*)ws;
  u16* qhT = (u16*)(ws + SZ);
  char* base = ws + 2 * SZ;
  u16* Wall   = (u16*)base;                       // 1.5 MB
  float* ctx  = (float*)(base + (2u << 20));      // 1 MB
  float* rsum = (float*)(base + (3u << 20));      // 16 KB
  u16* Weff   = (u16*)(base + (4u << 20));        // 4 MB
  (void)in_sizes; (void)n_in; (void)out_size; (void)ws_size;

  hipMemsetAsync(base + (2u << 20), 0, 2u << 20, stream);  // zero ctx + rowsum accumulators
  k_tq    <<<dim3(128, 8, 8), 256, 0, stream>>>(q, qT);
  k_cast_w<<<dim3(768), 256, 0, stream>>>(Wq, Wkv, Wall);
  k_proj  <<<dim3(6144), 256, 0, stream>>>(Wall, qT, qhT, ctx, rsum);
  k_weff  <<<dim3(8, 64), 256, 0, stream>>>(Wout, ctx, rsum, Weff);
  k_final <<<dim3(2048), 256, 0, stream>>>(Weff, qhT, bout, out);
}